// Round 2
// baseline (3721.358 us; speedup 1.0000x reference)
//
#include <hip/hip_runtime.h>

typedef unsigned short u16;
typedef unsigned int u32;
typedef __bf16 bf16x8 __attribute__((ext_vector_type(8)));
typedef float f32x4 __attribute__((ext_vector_type(4)));

#define HIDDEN 2048
#define SEQ 4096
#define HEADS 8
#define HD 256

__device__ __forceinline__ u16 f2bf(float f) {
  u32 u = __float_as_uint(f);
  u32 r = (u + 0x7fffu + ((u >> 16) & 1u)) >> 16;
  return (u16)r;
}
__device__ __forceinline__ float bf2f(u16 h) {
  return __uint_as_float(((u32)h) << 16);
}
__device__ __forceinline__ void async16(void* lds, const void* g) {
  __builtin_amdgcn_global_load_lds(
      (__attribute__((address_space(1))) void*)g,
      (__attribute__((address_space(3))) void*)lds, 16, 0, 0);
}

// ---------------- convert x to bf16 ----------------
__global__ __launch_bounds__(256) void k_cvt_x(const float* __restrict__ x,
                                               u16* __restrict__ xb) {
  int i = blockIdx.x * 256 + threadIdx.x;
  float4 v = ((const float4*)x)[i];
  ushort4 o;
  o.x = f2bf(v.x); o.y = f2bf(v.y); o.z = f2bf(v.z); o.w = f2bf(v.w);
  ((ushort4*)xb)[i] = o;
}

// ---------------- transpose weights to bf16 W^T[c][k] ----------------
__global__ __launch_bounds__(256) void k_transpose(
    const float* __restrict__ w0, const float* __restrict__ w1,
    const float* __restrict__ w2, const float* __restrict__ w3,
    const float* __restrict__ w4, u16* __restrict__ dst) {
  const float* src = (blockIdx.z == 0) ? w0 : (blockIdx.z == 1) ? w1
                   : (blockIdx.z == 2) ? w2 : (blockIdx.z == 3) ? w3 : w4;
  u16* out = dst + (size_t)blockIdx.z * HIDDEN * HIDDEN;
  __shared__ float tile[64 * 65];
  int k0 = blockIdx.y * 64, c0 = blockIdx.x * 64;
  int tid = threadIdx.x;
#pragma unroll
  for (int j = 0; j < 16; ++j) {
    int f = j * 256 + tid;
    int r = f >> 6, c = f & 63;
    tile[r * 65 + c] = src[(size_t)(k0 + r) * HIDDEN + c0 + c];
  }
  __syncthreads();
#pragma unroll
  for (int j = 0; j < 16; ++j) {
    int f = j * 256 + tid;
    int cc = f >> 6, kk = f & 63;
    out[(size_t)(c0 + cc) * HIDDEN + k0 + kk] = f2bf(tile[kk * 65 + cc]);
  }
}

// ---------------- GEMM: C[t][c] = A[t][:] . Bt[c][:] + bias ----------------
// MODE 0: rope epilogue -> bf16 [bh][n][d]   (q, k)
// MODE 1: bf16 transposed [bh][d][n]         (v)
// MODE 2: bf16 [t][c]                        (g)
// MODE 3: fp32 [t][c]                        (final out)
template <int MODE>
__global__ __launch_bounds__(256) void k_gemm(const u16* __restrict__ A,
                                              const u16* __restrict__ Bt,
                                              const float* __restrict__ bias,
                                              void* __restrict__ out) {
  __shared__ __align__(16) u16 Ab[128 * 32];
  __shared__ __align__(16) u16 Bb[128 * 32];
  const int tid = threadIdx.x;
  const int l = tid & 63, w = tid >> 6;
  const int wr = w >> 1, wc = w & 1;
  const int t0 = blockIdx.y * 128, c0 = blockIdx.x * 128;
  const int lr = l & 15, lk8 = (l >> 4) * 8;
  f32x4 acc[4][4] = {};
  for (int kk = 0; kk < HIDDEN; kk += 32) {
    __syncthreads();
#pragma unroll
    for (int j = 0; j < 2; ++j) {
      int ci = tid + 256 * j;
      async16((char*)Ab + (w * 64 + 256 * j) * 16,
              A + (size_t)(t0 + (ci >> 2)) * HIDDEN + kk + (ci & 3) * 8);
      async16((char*)Bb + (w * 64 + 256 * j) * 16,
              Bt + (size_t)(c0 + (ci >> 2)) * HIDDEN + kk + (ci & 3) * 8);
    }
    asm volatile("s_waitcnt vmcnt(0)" ::: "memory");
    __syncthreads();
    bf16x8 af[4], bfr[4];
#pragma unroll
    for (int m = 0; m < 4; ++m)
      af[m] = *(const bf16x8*)&Ab[(wr * 64 + m * 16 + lr) * 32 + lk8];
#pragma unroll
    for (int n = 0; n < 4; ++n)
      bfr[n] = *(const bf16x8*)&Bb[(wc * 64 + n * 16 + lr) * 32 + lk8];
#pragma unroll
    for (int m = 0; m < 4; ++m)
#pragma unroll
      for (int n = 0; n < 4; ++n)
        acc[m][n] = __builtin_amdgcn_mfma_f32_16x16x32_bf16(af[m], bfr[n],
                                                            acc[m][n], 0, 0, 0);
  }
#pragma unroll
  for (int m = 0; m < 4; ++m) {
#pragma unroll
    for (int n = 0; n < 4; ++n) {
      int cl = c0 + wc * 64 + n * 16 + lr;
#pragma unroll
      for (int r = 0; r < 4; ++r) {
        int tl = t0 + wr * 64 + m * 16 + (l >> 4) * 4 + r;
        float val = acc[m][n][r] + bias[cl];
        if constexpr (MODE == 0) {
          float pv = __shfl_xor(val, 1);
          float mi = (cl & 1) ? pv : -pv;  // even: -x_odd, odd: x_even
          int d = cl & 255, hh = cl >> 8;
          int ntok = tl & (SEQ - 1), bb = tl >> 12;
          float theta = exp2f(-(float)(d >> 1) * 0.1046276623f);  // log2(1e4)/127
          float sv, cv;
          sincosf((float)ntok * theta, &sv, &cv);
          float ov = val * cv + mi * sv;
          ((u16*)out)[((size_t)(bb * HEADS + hh) * SEQ + ntok) * HD + d] = f2bf(ov);
        } else if constexpr (MODE == 1) {
          int d = cl & 255, hh = cl >> 8;
          int ntok = tl & (SEQ - 1), bb = tl >> 12;
          ((u16*)out)[((size_t)(bb * HEADS + hh) * HD + d) * SEQ + ntok] = f2bf(val);
        } else if constexpr (MODE == 2) {
          ((u16*)out)[(size_t)tl * HIDDEN + cl] = f2bf(val);
        } else {
          ((float*)out)[(size_t)tl * HIDDEN + cl] = val;
        }
      }
    }
  }
}

// ---------------- retention attention ----------------
// per block: (q-tile of 64 rows) x (b,h); 4 waves, each 16 q-rows.
// output written as bf16 [t][c].
__global__ __launch_bounds__(256) void k_attn(const u16* __restrict__ qw,
                                              const u16* __restrict__ kw,
                                              const u16* __restrict__ vTw,
                                              u16* __restrict__ rtb) {
  __shared__ __align__(16) u16 k_lds[32 * 256];   // [s][d]
  __shared__ __align__(16) u16 vT_lds[256 * 32];  // [d][s]
  __shared__ __align__(16) u16 P_lds[64 * 32];    // [n][s]
  const int qx = blockIdx.x, bh = blockIdx.y;
  const int b = bh >> 3, h = bh & 7;
  const int tid = threadIdx.x, l = tid & 63, w = tid >> 6;
  const int lr = l & 15, lk8 = (l >> 4) * 8;
  const int q0 = qx * 64;
  const float log2g = log2f(1.0f - exp2f(-5.0f - 4.0f * (float)h / 7.0f));

  bf16x8 qf[8];
  {
    const u16* qbase = qw + ((size_t)bh * SEQ + q0 + w * 16 + lr) * HD + lk8;
#pragma unroll
    for (int kd = 0; kd < 8; ++kd) qf[kd] = *(const bf16x8*)(qbase + kd * 32);
  }
  f32x4 o[16] = {};
  const int s_stop = q0 + 64;
  for (int s0 = 0; s0 < s_stop; s0 += 32) {
    __syncthreads();
#pragma unroll
    for (int j = 0; j < 4; ++j) {
      int ci = tid + 256 * j;
      async16((char*)k_lds + (w * 64 + 256 * j) * 16,
              kw + ((size_t)bh * SEQ + s0 + (ci >> 5)) * HD + (ci & 31) * 8);
      async16((char*)vT_lds + (w * 64 + 256 * j) * 16,
              vTw + ((size_t)bh * HD + (ci >> 2)) * SEQ + s0 + (ci & 3) * 8);
    }
    asm volatile("s_waitcnt vmcnt(0)" ::: "memory");
    __syncthreads();
    // S = q . k^T  (16 rows x 32 cols per wave)
    f32x4 sf[2] = {};
#pragma unroll
    for (int fc = 0; fc < 2; ++fc)
#pragma unroll
      for (int kd = 0; kd < 8; ++kd) {
        bf16x8 kb = *(const bf16x8*)&k_lds[(fc * 16 + lr) * 256 + kd * 32 + lk8];
        sf[fc] = __builtin_amdgcn_mfma_f32_16x16x32_bf16(qf[kd], kb, sf[fc], 0, 0, 0);
      }
    // decay mask + 1/scale, write P as bf16
#pragma unroll
    for (int fc = 0; fc < 2; ++fc) {
      int s_l = fc * 16 + lr;
#pragma unroll
      for (int r = 0; r < 4; ++r) {
        int n_l = w * 16 + (l >> 4) * 4 + r;
        int dist = (q0 + n_l) - (s0 + s_l);
        float p = 0.0f;
        if (dist >= 0) p = sf[fc][r] * 0.0625f * exp2f((float)dist * log2g);
        P_lds[n_l * 32 + s_l] = f2bf(p);
      }
    }
    __syncthreads();
    // O += P . V
    bf16x8 pa = *(const bf16x8*)&P_lds[(w * 16 + lr) * 32 + lk8];
#pragma unroll
    for (int fd = 0; fd < 16; ++fd) {
      bf16x8 vb = *(const bf16x8*)&vT_lds[(fd * 16 + lr) * 32 + lk8];
      o[fd] = __builtin_amdgcn_mfma_f32_16x16x32_bf16(pa, vb, o[fd], 0, 0, 0);
    }
  }
  size_t trow = (size_t)b * SEQ + q0 + w * 16 + (l >> 4) * 4;
#pragma unroll
  for (int fd = 0; fd < 16; ++fd) {
    int c = h * HD + fd * 16 + lr;
#pragma unroll
    for (int r = 0; r < 4; ++r)
      rtb[(trow + r) * HIDDEN + c] = f2bf(o[fd][r]);
  }
}

// ---------------- groupnorm + silu gate (in-place on bf16 ret) ----------------
__global__ __launch_bounds__(256) void k_gate(u16* __restrict__ rg,
                                              const u16* __restrict__ gw,
                                              const float* __restrict__ gnw,
                                              const float* __restrict__ gnb) {
  int g = blockIdx.x * 4 + (threadIdx.x >> 6);
  int l = threadIdx.x & 63;
  int t = g >> 3, h = g & 7;
  size_t base = (size_t)t * HIDDEN + h * HD + l * 4;
  ushort4 r4 = *(const ushort4*)(rg + base);
  float rv[4] = {bf2f(r4.x), bf2f(r4.y), bf2f(r4.z), bf2f(r4.w)};
  float s = rv[0] + rv[1] + rv[2] + rv[3];
  float sq = rv[0] * rv[0] + rv[1] * rv[1] + rv[2] * rv[2] + rv[3] * rv[3];
#pragma unroll
  for (int off = 32; off > 0; off >>= 1) {
    s += __shfl_xor(s, off);
    sq += __shfl_xor(sq, off);
  }
  float mean = s * (1.0f / 256.0f);
  float var = sq * (1.0f / 256.0f) - mean * mean;
  float rstd = rsqrtf(var + 1e-5f);
  int cb = h * HD + l * 4;
  float4 wv = *(const float4*)(gnw + cb);
  float4 bv = *(const float4*)(gnb + cb);
  ushort4 gg = *(const ushort4*)(gw + base);
  float gf[4] = {bf2f(gg.x), bf2f(gg.y), bf2f(gg.z), bf2f(gg.w)};
  float wa[4] = {wv.x, wv.y, wv.z, wv.w};
  float ba[4] = {bv.x, bv.y, bv.z, bv.w};
  ushort4 ov;
  u16* po = (u16*)&ov;
#pragma unroll
  for (int e = 0; e < 4; ++e) {
    float nrm = (rv[e] - mean) * rstd * wa[e] + ba[e];
    float gv = gf[e];
    float si = gv / (1.0f + expf(-gv));
    po[e] = f2bf(si * nrm);
  }
  *(ushort4*)(rg + base) = ov;
}

extern "C" void kernel_launch(void* const* d_in, const int* in_sizes, int n_in,
                              void* d_out, int out_size, void* d_ws, size_t ws_size,
                              hipStream_t stream) {
  (void)in_sizes; (void)n_in; (void)out_size; (void)ws_size;
  const float* x   = (const float*)d_in[0];
  const float* w_q = (const float*)d_in[1];
  const float* b_q = (const float*)d_in[2];
  const float* w_k = (const float*)d_in[3];
  const float* b_k = (const float*)d_in[4];
  const float* w_v = (const float*)d_in[5];
  const float* b_v = (const float*)d_in[6];
  const float* w_g = (const float*)d_in[7];
  const float* b_g = (const float*)d_in[8];
  const float* w_o = (const float*)d_in[9];
  const float* b_o = (const float*)d_in[10];
  const float* gnw = (const float*)d_in[11];
  const float* gnb = (const float*)d_in[12];

  // workspace layout — peak 209,715,200 B = 200 MiB:
  //   slot0: xb (bf16 x) -> later ret/gate bf16 (in-place)   33.5 MB
  //   wT:    5x transposed bf16 weights                      41.9 MB
  //   qw, kw, vTw, gw: bf16 activations                      4x 33.5 MB
  char* ws = (char*)d_ws;
  u16* xb   = (u16*)(ws);
  u16* wT   = (u16*)(ws + 33554432ULL);
  u16* qw   = (u16*)(ws + 75497472ULL);
  u16* kw   = (u16*)(ws + 109051904ULL);
  u16* vTw  = (u16*)(ws + 142606336ULL);
  u16* gw   = (u16*)(ws + 176160768ULL);
  u16* rtg  = xb;  // ret/gate reuse slot0 (xb dead after g-GEMM)

  const size_t WSZ = 4194304;  // elements per transposed weight matrix

  k_cvt_x<<<16384, 256, 0, stream>>>(x, xb);
  k_transpose<<<dim3(32, 32, 5), 256, 0, stream>>>(w_q, w_k, w_v, w_g, w_o, wT);
  k_gemm<0><<<dim3(16, 64), 256, 0, stream>>>(xb, wT,           b_q, (void*)qw);
  k_gemm<0><<<dim3(16, 64), 256, 0, stream>>>(xb, wT + WSZ,     b_k, (void*)kw);
  k_gemm<1><<<dim3(16, 64), 256, 0, stream>>>(xb, wT + 2 * WSZ, b_v, (void*)vTw);
  k_gemm<2><<<dim3(16, 64), 256, 0, stream>>>(xb, wT + 3 * WSZ, b_g, (void*)gw);
  k_attn<<<dim3(64, 16), 256, 0, stream>>>(qw, kw, vTw, rtg);
  k_gate<<<16384, 256, 0, stream>>>(rtg, gw, gnw, gnb);
  k_gemm<3><<<dim3(16, 64), 256, 0, stream>>>(rtg, wT + 4 * WSZ, b_o, d_out);
}

// Round 4
// 3448.896 us; speedup vs baseline: 1.0790x; 1.0790x over previous
//
#include <hip/hip_runtime.h>

typedef unsigned short u16;
typedef unsigned int u32;
typedef __bf16 bf16x8 __attribute__((ext_vector_type(8)));
typedef float f32x4 __attribute__((ext_vector_type(4)));

#define HIDDEN 2048
#define SEQ 4096
#define HEADS 8
#define HD 256

__device__ __forceinline__ u16 f2bf(float f) {
  u32 u = __float_as_uint(f);
  u32 r = (u + 0x7fffu + ((u >> 16) & 1u)) >> 16;
  return (u16)r;
}
__device__ __forceinline__ float bf2f(u16 h) {
  return __uint_as_float(((u32)h) << 16);
}
__device__ __forceinline__ void async16(void* lds, const void* g) {
  __builtin_amdgcn_global_load_lds(
      (__attribute__((address_space(1))) void*)g,
      (__attribute__((address_space(3))) void*)lds, 16, 0, 0);
}

// ---------------- convert x to bf16 ----------------
__global__ __launch_bounds__(256) void k_cvt_x(const float* __restrict__ x,
                                               u16* __restrict__ xb) {
  int i = blockIdx.x * 256 + threadIdx.x;
  float4 v = ((const float4*)x)[i];
  ushort4 o;
  o.x = f2bf(v.x); o.y = f2bf(v.y); o.z = f2bf(v.z); o.w = f2bf(v.w);
  ((ushort4*)xb)[i] = o;
}

// ---------------- transpose weights to bf16 W^T[c][k] ----------------
__global__ __launch_bounds__(256) void k_transpose(
    const float* __restrict__ w0, const float* __restrict__ w1,
    const float* __restrict__ w2, const float* __restrict__ w3,
    const float* __restrict__ w4, u16* __restrict__ dst) {
  const float* src = (blockIdx.z == 0) ? w0 : (blockIdx.z == 1) ? w1
                   : (blockIdx.z == 2) ? w2 : (blockIdx.z == 3) ? w3 : w4;
  u16* out = dst + (size_t)blockIdx.z * HIDDEN * HIDDEN;
  __shared__ float tile[64 * 65];
  int k0 = blockIdx.y * 64, c0 = blockIdx.x * 64;
  int tid = threadIdx.x;
#pragma unroll
  for (int j = 0; j < 16; ++j) {
    int f = j * 256 + tid;
    int r = f >> 6, c = f & 63;
    tile[r * 65 + c] = src[(size_t)(k0 + r) * HIDDEN + c0 + c];
  }
  __syncthreads();
#pragma unroll
  for (int j = 0; j < 16; ++j) {
    int f = j * 256 + tid;
    int cc = f >> 6, kk = f & 63;
    out[(size_t)(c0 + cc) * HIDDEN + k0 + kk] = f2bf(tile[kk * 65 + cc]);
  }
}

// ---------------- GEMM: C[t][c] = A[t][:] . Bt[c][:] + bias ----------------
// 128x128 tile, BK=32, 2-phase double-buffered staging, swizzled LDS.
// LDS tile [128 r][4 chunks of 8 u16]; chunk' = chunk ^ ((r>>1)&3).
// MODE 0: rope epilogue -> bf16 [bh][n][d]   (q, k)
// MODE 1: bf16 transposed [bh][d][n]         (v)  — ushort4 stores
// MODE 2: bf16 [t][c]                        (g)
// MODE 3: fp32 [t][c]                        (final out)
template <int MODE>
__global__ __launch_bounds__(256) void k_gemm(const u16* __restrict__ A,
                                              const u16* __restrict__ Bt,
                                              const float* __restrict__ bias,
                                              void* __restrict__ out) {
  __shared__ __align__(16) u16 Ab[2][128 * 32];
  __shared__ __align__(16) u16 Bb[2][128 * 32];
  const int tid = threadIdx.x;
  const int l = tid & 63, w = tid >> 6;
  const int wr = w >> 1, wc = w & 1;
  const int t0 = blockIdx.y * 128, c0 = blockIdx.x * 128;
  const int lr = l & 15;
  const int cs8 = (((l >> 4) ^ ((lr >> 1) & 3)) * 8);  // swizzled k-chunk (u16 idx)
  // staging source offsets (swizzled column within 32-elem K-slab)
  const int ci0 = tid, ci1 = tid + 256;
  const size_t aoff0 = (size_t)(t0 + (ci0 >> 2)) * HIDDEN + (((ci0 & 3) ^ ((ci0 >> 3) & 3)) * 8);
  const size_t aoff1 = (size_t)(t0 + (ci1 >> 2)) * HIDDEN + (((ci1 & 3) ^ ((ci1 >> 3) & 3)) * 8);
  const size_t boff0 = (size_t)(c0 + (ci0 >> 2)) * HIDDEN + (((ci0 & 3) ^ ((ci0 >> 3) & 3)) * 8);
  const size_t boff1 = (size_t)(c0 + (ci1 >> 2)) * HIDDEN + (((ci1 & 3) ^ ((ci1 >> 3) & 3)) * 8);
  const int ldsb = w * 1024;  // wave-uniform LDS byte base (64 lanes * 16B)

  f32x4 acc[4][4] = {};
#define GSTAGE(buf, kk)                                              \
  do {                                                               \
    async16((char*)&Ab[buf][0] + ldsb, A + aoff0 + (kk));            \
    async16((char*)&Ab[buf][0] + ldsb + 4096, A + aoff1 + (kk));     \
    async16((char*)&Bb[buf][0] + ldsb, Bt + boff0 + (kk));           \
    async16((char*)&Bb[buf][0] + ldsb + 4096, Bt + boff1 + (kk));    \
  } while (0)

  GSTAGE(0, 0);
  asm volatile("s_waitcnt vmcnt(0)" ::: "memory");
  __syncthreads();
  int cur = 0;
  for (int kk = 0; kk < HIDDEN; kk += 32) {
    if (kk + 32 < HIDDEN) GSTAGE(cur ^ 1, kk + 32);
    bf16x8 af[4], bfr[4];
#pragma unroll
    for (int m = 0; m < 4; ++m)
      af[m] = *(const bf16x8*)&Ab[cur][(wr * 64 + m * 16 + lr) * 32 + cs8];
#pragma unroll
    for (int n = 0; n < 4; ++n)
      bfr[n] = *(const bf16x8*)&Bb[cur][(wc * 64 + n * 16 + lr) * 32 + cs8];
#pragma unroll
    for (int m = 0; m < 4; ++m)
#pragma unroll
      for (int n = 0; n < 4; ++n)
        acc[m][n] = __builtin_amdgcn_mfma_f32_16x16x32_bf16(af[m], bfr[n],
                                                            acc[m][n], 0, 0, 0);
    asm volatile("s_waitcnt vmcnt(0)" ::: "memory");
    __syncthreads();
    cur ^= 1;
  }
#undef GSTAGE

#pragma unroll
  for (int m = 0; m < 4; ++m) {
#pragma unroll
    for (int n = 0; n < 4; ++n) {
      int cl = c0 + wc * 64 + n * 16 + lr;
      int tlb = t0 + wr * 64 + m * 16 + (l >> 4) * 4;
      if constexpr (MODE == 1) {
        int d = cl & 255, hh = cl >> 8;
        int nb = tlb & (SEQ - 1), bb = tlb >> 12;
        float bi = bias[cl];
        ushort4 ov;
        ov.x = f2bf(acc[m][n][0] + bi);
        ov.y = f2bf(acc[m][n][1] + bi);
        ov.z = f2bf(acc[m][n][2] + bi);
        ov.w = f2bf(acc[m][n][3] + bi);
        *(ushort4*)&((u16*)out)[((size_t)(bb * HEADS + hh) * HD + d) * SEQ + nb] = ov;
      } else {
#pragma unroll
        for (int r = 0; r < 4; ++r) {
          int tl = tlb + r;
          float val = acc[m][n][r] + bias[cl];
          if constexpr (MODE == 0) {
            float pv = __shfl_xor(val, 1);
            float mi = (cl & 1) ? pv : -pv;  // even: -x_odd, odd: x_even
            int d = cl & 255, hh = cl >> 8;
            int ntok = tl & (SEQ - 1), bb = tl >> 12;
            float theta = exp2f(-(float)(d >> 1) * 0.1046276623f);
            float sv, cv;
            sincosf((float)ntok * theta, &sv, &cv);
            float ov = val * cv + mi * sv;
            ((u16*)out)[((size_t)(bb * HEADS + hh) * SEQ + ntok) * HD + d] = f2bf(ov);
          } else if constexpr (MODE == 2) {
            ((u16*)out)[(size_t)tl * HIDDEN + cl] = f2bf(val);
          } else {
            ((float*)out)[(size_t)tl * HIDDEN + cl] = val;
          }
        }
      }
    }
  }
}

// ---------------- retention attention ----------------
// per block: (q-tile of 64 rows) x (b,h); 4 waves, each 16 q-rows.
// K tile [32 s][32 chunks]: chunk' = chunk ^ (s&7)        (conflict-free)
// V^T tile [256 d][4 chunks]: chunk' = chunk ^ ((d>>1)&3) (conflict-free)
// P tile [64 n][4 chunks]:  chunk' = chunk ^ ((n>>1)&3)   (write AND read swizzled)
// P tile wave-private -> no mid-step barrier; 2-phase staged K/V.
__global__ __launch_bounds__(256) void k_attn(const u16* __restrict__ qw,
                                              const u16* __restrict__ kw,
                                              const u16* __restrict__ vTw,
                                              u16* __restrict__ rtb) {
  __shared__ __align__(16) u16 k_lds[2][32 * 256];
  __shared__ __align__(16) u16 vT_lds[2][256 * 32];
  __shared__ __align__(16) u16 P_lds[64 * 32];
  const int qx = blockIdx.x, bh = blockIdx.y;
  const int b = bh >> 3, h = bh & 7;
  const int tid = threadIdx.x, l = tid & 63, w = tid >> 6;
  const int lr = l & 15, lk8 = (l >> 4) * 8;
  const int q0 = qx * 64;
  const float log2g = log2f(1.0f - exp2f(-5.0f - 4.0f * (float)h / 7.0f));
  const int cs_v8 = (((l >> 4) ^ ((lr >> 1) & 3)) * 8);
  const int lr7 = lr & 7;

  bf16x8 qf[8];
  {
    const u16* qbase = qw + ((size_t)bh * SEQ + q0 + w * 16 + lr) * HD + lk8;
#pragma unroll
    for (int kd = 0; kd < 8; ++kd) qf[kd] = *(const bf16x8*)(qbase + kd * 32);
  }
  // staging source offsets (function of lane; + s0-dependent term added per step)
  size_t koff[4], voff[4];
#pragma unroll
  for (int j = 0; j < 4; ++j) {
    int ci = tid + 256 * j;
    koff[j] = ((size_t)bh * SEQ + (ci >> 5)) * HD + (((ci & 31) ^ ((ci >> 5) & 7)) * 8);
    voff[j] = ((size_t)bh * HD + (ci >> 2)) * SEQ + (((ci & 3) ^ ((ci >> 3) & 3)) * 8);
  }
  const int ldsb = w * 1024;

#define ASTAGE(buf, s0)                                                        \
  do {                                                                         \
    _Pragma("unroll") for (int j = 0; j < 4; ++j) {                            \
      async16((char*)&k_lds[buf][0] + ldsb + j * 4096,                         \
              kw + koff[j] + (size_t)(s0)*HD);                                 \
      async16((char*)&vT_lds[buf][0] + ldsb + j * 4096,                        \
              vTw + voff[j] + (size_t)(s0));                                   \
    }                                                                          \
  } while (0)

  f32x4 o[16] = {};
  const int nt = qx * 2 + 2;
  ASTAGE(0, 0);
  asm volatile("s_waitcnt vmcnt(0)" ::: "memory");
  __syncthreads();
  int cur = 0;
  for (int t = 0; t < nt; ++t) {
    const int s0 = t * 32;
    if (t + 1 < nt) ASTAGE(cur ^ 1, s0 + 32);
    // S = q . k^T  (16 rows x 32 cols per wave)
    f32x4 sf[2] = {};
#pragma unroll
    for (int fc = 0; fc < 2; ++fc) {
      const int R = fc * 16 + lr;
#pragma unroll
      for (int kd = 0; kd < 8; ++kd) {
        bf16x8 kb = *(const bf16x8*)&k_lds[cur][R * 256 + (((kd * 4 + (l >> 4)) ^ lr7) * 8)];
        sf[fc] = __builtin_amdgcn_mfma_f32_16x16x32_bf16(qf[kd], kb, sf[fc], 0, 0, 0);
      }
    }
    // decay mask + 1/scale, write P bf16 (wave-private rows, swizzled chunks)
#pragma unroll
    for (int fc = 0; fc < 2; ++fc) {
      int s_l = fc * 16 + lr;
      int chunk = s_l >> 3;
#pragma unroll
      for (int r = 0; r < 4; ++r) {
        int n_l = w * 16 + (l >> 4) * 4 + r;
        int dist = (q0 + n_l) - (s0 + s_l);
        float p = 0.0f;
        if (dist >= 0) p = sf[fc][r] * 0.0625f * exp2f((float)dist * log2g);
        P_lds[n_l * 32 + ((chunk ^ ((n_l >> 1) & 3)) * 8) + (s_l & 7)] = f2bf(p);
      }
    }
    // O += P . V   (same-wave RAW on P_lds ordered by lgkmcnt)
    bf16x8 pa = *(const bf16x8*)&P_lds[(w * 16 + lr) * 32 + cs_v8];
#pragma unroll
    for (int fd = 0; fd < 16; ++fd) {
      bf16x8 vb = *(const bf16x8*)&vT_lds[cur][(fd * 16 + lr) * 32 + cs_v8];
      o[fd] = __builtin_amdgcn_mfma_f32_16x16x32_bf16(pa, vb, o[fd], 0, 0, 0);
    }
    asm volatile("s_waitcnt vmcnt(0)" ::: "memory");
    __syncthreads();
    cur ^= 1;
  }
#undef ASTAGE
  size_t trow = (size_t)b * SEQ + q0 + w * 16 + (l >> 4) * 4;
#pragma unroll
  for (int fd = 0; fd < 16; ++fd) {
    int c = h * HD + fd * 16 + lr;
#pragma unroll
    for (int r = 0; r < 4; ++r)
      rtb[(trow + r) * HIDDEN + c] = f2bf(o[fd][r]);
  }
}

// ---------------- groupnorm + silu gate (in-place on bf16 ret) ----------------
__global__ __launch_bounds__(256) void k_gate(u16* __restrict__ rg,
                                              const u16* __restrict__ gw,
                                              const float* __restrict__ gnw,
                                              const float* __restrict__ gnb) {
  int g = blockIdx.x * 4 + (threadIdx.x >> 6);
  int l = threadIdx.x & 63;
  int t = g >> 3, h = g & 7;
  size_t base = (size_t)t * HIDDEN + h * HD + l * 4;
  ushort4 r4 = *(const ushort4*)(rg + base);
  float rv[4] = {bf2f(r4.x), bf2f(r4.y), bf2f(r4.z), bf2f(r4.w)};
  float s = rv[0] + rv[1] + rv[2] + rv[3];
  float sq = rv[0] * rv[0] + rv[1] * rv[1] + rv[2] * rv[2] + rv[3] * rv[3];
#pragma unroll
  for (int off = 32; off > 0; off >>= 1) {
    s += __shfl_xor(s, off);
    sq += __shfl_xor(sq, off);
  }
  float mean = s * (1.0f / 256.0f);
  float var = sq * (1.0f / 256.0f) - mean * mean;
  float rstd = rsqrtf(var + 1e-5f);
  int cb = h * HD + l * 4;
  float4 wv = *(const float4*)(gnw + cb);
  float4 bv = *(const float4*)(gnb + cb);
  ushort4 gg = *(const ushort4*)(gw + base);
  float gf[4] = {bf2f(gg.x), bf2f(gg.y), bf2f(gg.z), bf2f(gg.w)};
  float wa[4] = {wv.x, wv.y, wv.z, wv.w};
  float ba[4] = {bv.x, bv.y, bv.z, bv.w};
  ushort4 ov;
  u16* po = (u16*)&ov;
#pragma unroll
  for (int e = 0; e < 4; ++e) {
    float nrm = (rv[e] - mean) * rstd * wa[e] + ba[e];
    float gv = gf[e];
    float si = gv / (1.0f + expf(-gv));
    po[e] = f2bf(si * nrm);
  }
  *(ushort4*)(rg + base) = ov;
}

extern "C" void kernel_launch(void* const* d_in, const int* in_sizes, int n_in,
                              void* d_out, int out_size, void* d_ws, size_t ws_size,
                              hipStream_t stream) {
  (void)in_sizes; (void)n_in; (void)out_size; (void)ws_size;
  const float* x   = (const float*)d_in[0];
  const float* w_q = (const float*)d_in[1];
  const float* b_q = (const float*)d_in[2];
  const float* w_k = (const float*)d_in[3];
  const float* b_k = (const float*)d_in[4];
  const float* w_v = (const float*)d_in[5];
  const float* b_v = (const float*)d_in[6];
  const float* w_g = (const float*)d_in[7];
  const float* b_g = (const float*)d_in[8];
  const float* w_o = (const float*)d_in[9];
  const float* b_o = (const float*)d_in[10];
  const float* gnw = (const float*)d_in[11];
  const float* gnb = (const float*)d_in[12];

  // workspace layout — peak 200 MiB
  char* ws = (char*)d_ws;
  u16* xb   = (u16*)(ws);
  u16* wT   = (u16*)(ws + 33554432ULL);
  u16* qw   = (u16*)(ws + 75497472ULL);
  u16* kw   = (u16*)(ws + 109051904ULL);
  u16* vTw  = (u16*)(ws + 142606336ULL);
  u16* gw   = (u16*)(ws + 176160768ULL);
  u16* rtg  = xb;  // ret/gate reuse slot0 (xb dead after g-GEMM)

  const size_t WSZ = 4194304;  // elements per transposed weight matrix

  k_cvt_x<<<16384, 256, 0, stream>>>(x, xb);
  k_transpose<<<dim3(32, 32, 5), 256, 0, stream>>>(w_q, w_k, w_v, w_g, w_o, wT);
  k_gemm<0><<<dim3(16, 64), 256, 0, stream>>>(xb, wT,           b_q, (void*)qw);
  k_gemm<0><<<dim3(16, 64), 256, 0, stream>>>(xb, wT + WSZ,     b_k, (void*)kw);
  k_gemm<1><<<dim3(16, 64), 256, 0, stream>>>(xb, wT + 2 * WSZ, b_v, (void*)vTw);
  k_gemm<2><<<dim3(16, 64), 256, 0, stream>>>(xb, wT + 3 * WSZ, b_g, (void*)gw);
  k_attn<<<dim3(64, 16), 256, 0, stream>>>(qw, kw, vTw, rtg);
  k_gate<<<16384, 256, 0, stream>>>(rtg, gw, gnw, gnb);
  k_gemm<3><<<dim3(16, 64), 256, 0, stream>>>(rtg, wT + 4 * WSZ, b_o, d_out);
}

// Round 5
// 3017.662 us; speedup vs baseline: 1.2332x; 1.1429x over previous
//
#include <hip/hip_runtime.h>

typedef unsigned short u16;
typedef unsigned int u32;
typedef __bf16 bf16x8 __attribute__((ext_vector_type(8)));
typedef float f32x4 __attribute__((ext_vector_type(4)));

#define HIDDEN 2048
#define SEQ 4096
#define HEADS 8
#define HD 256

__device__ __forceinline__ u16 f2bf(float f) {
  u32 u = __float_as_uint(f);
  u32 r = (u + 0x7fffu + ((u >> 16) & 1u)) >> 16;
  return (u16)r;
}
__device__ __forceinline__ float bf2f(u16 h) {
  return __uint_as_float(((u32)h) << 16);
}
__device__ __forceinline__ void async16(void* lds, const void* g) {
  __builtin_amdgcn_global_load_lds(
      (__attribute__((address_space(1))) void*)g,
      (__attribute__((address_space(3))) void*)lds, 16, 0, 0);
}

// ---------------- convert x to bf16 ----------------
__global__ __launch_bounds__(256) void k_cvt_x(const float* __restrict__ x,
                                               u16* __restrict__ xb) {
  int i = blockIdx.x * 256 + threadIdx.x;
  float4 v = ((const float4*)x)[i];
  ushort4 o;
  o.x = f2bf(v.x); o.y = f2bf(v.y); o.z = f2bf(v.z); o.w = f2bf(v.w);
  ((ushort4*)xb)[i] = o;
}

// ---------------- transpose weights to bf16 W^T[c][k] ----------------
__global__ __launch_bounds__(256) void k_transpose(
    const float* __restrict__ w0, const float* __restrict__ w1,
    const float* __restrict__ w2, const float* __restrict__ w3,
    const float* __restrict__ w4, u16* __restrict__ dst) {
  const float* src = (blockIdx.z == 0) ? w0 : (blockIdx.z == 1) ? w1
                   : (blockIdx.z == 2) ? w2 : (blockIdx.z == 3) ? w3 : w4;
  u16* out = dst + (size_t)blockIdx.z * HIDDEN * HIDDEN;
  __shared__ float tile[64 * 65];
  int k0 = blockIdx.y * 64, c0 = blockIdx.x * 64;
  int tid = threadIdx.x;
#pragma unroll
  for (int j = 0; j < 16; ++j) {
    int f = j * 256 + tid;
    int r = f >> 6, c = f & 63;
    tile[r * 65 + c] = src[(size_t)(k0 + r) * HIDDEN + c0 + c];
  }
  __syncthreads();
#pragma unroll
  for (int j = 0; j < 16; ++j) {
    int f = j * 256 + tid;
    int cc = f >> 6, kk = f & 63;
    out[(size_t)(c0 + cc) * HIDDEN + k0 + kk] = f2bf(tile[kk * 65 + cc]);
  }
}

// ---------------- GEMM body: C[t][c] = A[t][:] . Bt[c][:] + bias ----------------
// 128x128 tile, BK=32, double-buffered global_load_lds, swizzled LDS
// (verified round-4 algebra, unchanged).
// MODE 0: rope epilogue -> bf16 [bh][n][d]   (q, k)
// MODE 1: bf16 transposed [bh][d][n]         (v)  — ushort4 stores
// MODE 2: bf16 [t][c]                        (g)
// MODE 3: fp32 [t][c]                        (final out)
template <int MODE>
__device__ __forceinline__ void gemm_body(const u16* __restrict__ A,
                                          const u16* __restrict__ Bt,
                                          const float* __restrict__ bias,
                                          void* __restrict__ out,
                                          int bx, int by, u16* Ab, u16* Bb) {
  const int tid = threadIdx.x;
  const int l = tid & 63, w = tid >> 6;
  const int wr = w >> 1, wc = w & 1;
  const int t0 = by * 128, c0 = bx * 128;
  const int lr = l & 15;
  const int cs8 = (((l >> 4) ^ ((lr >> 1) & 3)) * 8);  // swizzled k-chunk (u16 idx)
  const int ci0 = tid, ci1 = tid + 256;
  const size_t aoff0 = (size_t)(t0 + (ci0 >> 2)) * HIDDEN + (((ci0 & 3) ^ ((ci0 >> 3) & 3)) * 8);
  const size_t aoff1 = (size_t)(t0 + (ci1 >> 2)) * HIDDEN + (((ci1 & 3) ^ ((ci1 >> 3) & 3)) * 8);
  const size_t boff0 = (size_t)(c0 + (ci0 >> 2)) * HIDDEN + (((ci0 & 3) ^ ((ci0 >> 3) & 3)) * 8);
  const size_t boff1 = (size_t)(c0 + (ci1 >> 2)) * HIDDEN + (((ci1 & 3) ^ ((ci1 >> 3) & 3)) * 8);
  const int ldsb = w * 1024;  // wave-uniform LDS byte base

  f32x4 acc[4][4] = {};
#define GSTAGE(buf, kk)                                                  \
  do {                                                                   \
    async16((char*)Ab + (buf)*8192 + ldsb, A + aoff0 + (kk));            \
    async16((char*)Ab + (buf)*8192 + ldsb + 4096, A + aoff1 + (kk));     \
    async16((char*)Bb + (buf)*8192 + ldsb, Bt + boff0 + (kk));           \
    async16((char*)Bb + (buf)*8192 + ldsb + 4096, Bt + boff1 + (kk));    \
  } while (0)

  GSTAGE(0, 0);
  asm volatile("s_waitcnt vmcnt(0)" ::: "memory");
  __syncthreads();
  int cur = 0;
  for (int kk = 0; kk < HIDDEN; kk += 32) {
    if (kk + 32 < HIDDEN) GSTAGE(cur ^ 1, kk + 32);
    bf16x8 af[4], bfr[4];
#pragma unroll
    for (int m = 0; m < 4; ++m)
      af[m] = *(const bf16x8*)&Ab[cur * 4096 + (wr * 64 + m * 16 + lr) * 32 + cs8];
#pragma unroll
    for (int n = 0; n < 4; ++n)
      bfr[n] = *(const bf16x8*)&Bb[cur * 4096 + (wc * 64 + n * 16 + lr) * 32 + cs8];
#pragma unroll
    for (int m = 0; m < 4; ++m)
#pragma unroll
      for (int n = 0; n < 4; ++n)
        acc[m][n] = __builtin_amdgcn_mfma_f32_16x16x32_bf16(af[m], bfr[n],
                                                            acc[m][n], 0, 0, 0);
    asm volatile("s_waitcnt vmcnt(0)" ::: "memory");
    __syncthreads();
    cur ^= 1;
  }
#undef GSTAGE

#pragma unroll
  for (int m = 0; m < 4; ++m) {
#pragma unroll
    for (int n = 0; n < 4; ++n) {
      int cl = c0 + wc * 64 + n * 16 + lr;
      int tlb = t0 + wr * 64 + m * 16 + (l >> 4) * 4;
      if constexpr (MODE == 1) {
        int d = cl & 255, hh = cl >> 8;
        int nb = tlb & (SEQ - 1), bb = tlb >> 12;
        float bi = bias[cl];
        ushort4 ov;
        ov.x = f2bf(acc[m][n][0] + bi);
        ov.y = f2bf(acc[m][n][1] + bi);
        ov.z = f2bf(acc[m][n][2] + bi);
        ov.w = f2bf(acc[m][n][3] + bi);
        *(ushort4*)&((u16*)out)[((size_t)(bb * HEADS + hh) * HD + d) * SEQ + nb] = ov;
      } else {
#pragma unroll
        for (int r = 0; r < 4; ++r) {
          int tl = tlb + r;
          float val = acc[m][n][r] + bias[cl];
          if constexpr (MODE == 0) {
            float pv = __shfl_xor(val, 1);
            float mi = (cl & 1) ? pv : -pv;  // even: -x_odd, odd: x_even
            int d = cl & 255, hh = cl >> 8;
            int ntok = tl & (SEQ - 1), bb = tl >> 12;
            float theta = exp2f(-(float)(d >> 1) * 0.1046276623f);
            float sv, cv;
            sincosf((float)ntok * theta, &sv, &cv);
            float ov = val * cv + mi * sv;
            ((u16*)out)[((size_t)(bb * HEADS + hh) * SEQ + ntok) * HD + d] = f2bf(ov);
          } else if constexpr (MODE == 2) {
            ((u16*)out)[(size_t)tl * HIDDEN + cl] = f2bf(val);
          } else {
            ((float*)out)[(size_t)tl * HIDDEN + cl] = val;
          }
        }
      }
    }
  }
}

// Fused Q/K/V/G projection: 4096 blocks, XCD-owns-A-strip remap.
__global__ __launch_bounds__(256) void k_gemm_qkvg(
    const u16* __restrict__ A, const u16* __restrict__ wT,
    const float* __restrict__ b_q, const float* __restrict__ b_k,
    const float* __restrict__ b_v, const float* __restrict__ b_g,
    u16* __restrict__ qw, u16* __restrict__ kw, u16* __restrict__ vTw,
    u16* __restrict__ gw) {
  __shared__ __align__(16) u16 Ab[2 * 128 * 32];
  __shared__ __align__(16) u16 Bb[2 * 128 * 32];
  const int id = blockIdx.x;
  const int xcd = id & 7, j = id >> 3;      // j: 0..511
  const int by = xcd * 8 + (j & 7);         // each XCD owns 8 A-panels
  const int BX = j >> 3;                    // 0..63 global c-block
  const int wsel = BX >> 4, bx = BX & 15;
  const size_t WSZ = 4194304;
  switch (wsel) {
    case 0: gemm_body<0>(A, wT,           b_q, (void*)qw,  bx, by, Ab, Bb); break;
    case 1: gemm_body<0>(A, wT + WSZ,     b_k, (void*)kw,  bx, by, Ab, Bb); break;
    case 2: gemm_body<1>(A, wT + 2 * WSZ, b_v, (void*)vTw, bx, by, Ab, Bb); break;
    default: gemm_body<2>(A, wT + 3 * WSZ, b_g, (void*)gw, bx, by, Ab, Bb); break;
  }
}

// Output projection: 1024 blocks, same XCD remap.
__global__ __launch_bounds__(256) void k_gemm_o(const u16* __restrict__ A,
                                                const u16* __restrict__ Bt,
                                                const float* __restrict__ bias,
                                                float* __restrict__ out) {
  __shared__ __align__(16) u16 Ab[2 * 128 * 32];
  __shared__ __align__(16) u16 Bb[2 * 128 * 32];
  const int id = blockIdx.x;
  const int xcd = id & 7, j = id >> 3;      // j: 0..127
  const int by = xcd * 8 + (j & 7);
  const int bx = j >> 3;                    // 0..15
  gemm_body<3>(A, Bt, bias, (void*)out, bx, by, Ab, Bb);
}

// ---------------- retention attention ----------------
// Tq=128 (8 waves, 512 thr), Tk=32 double-buffered; bh pinned 2-per-XCD.
// K tile [32 s][32 chunks]: chunk' = chunk ^ (s&7)
// V^T tile [256 d][4 chunks]: chunk' = chunk ^ ((d>>1)&3)
// P tile [128 n][4 chunks]:  chunk' = chunk ^ ((n>>1)&3) (write+read swizzled)
__global__ __launch_bounds__(512) void k_attn(const u16* __restrict__ qw,
                                              const u16* __restrict__ kw,
                                              const u16* __restrict__ vTw,
                                              u16* __restrict__ rtb) {
  __shared__ __align__(16) u16 k_lds[2][32 * 256];
  __shared__ __align__(16) u16 vT_lds[2][256 * 32];
  __shared__ __align__(16) u16 P_lds[128 * 32];
  const int id = blockIdx.x;
  const int bh = ((id & 7) << 1) | ((id >> 3) & 1);  // 2 heads per XCD
  const int qx = id >> 4;                            // 0..31
  const int b = bh >> 3, h = bh & 7;
  const int tid = threadIdx.x, l = tid & 63, w = tid >> 6;
  const int lr = l & 15, lk8 = (l >> 4) * 8;
  const int q0 = qx * 128;
  const float log2g = log2f(1.0f - exp2f(-5.0f - 4.0f * (float)h / 7.0f));
  const int cs_v8 = (((l >> 4) ^ ((lr >> 1) & 3)) * 8);
  const int lr7 = lr & 7;

  bf16x8 qf[8];
  {
    const u16* qbase = qw + ((size_t)bh * SEQ + q0 + w * 16 + lr) * HD + lk8;
#pragma unroll
    for (int kd = 0; kd < 8; ++kd) qf[kd] = *(const bf16x8*)(qbase + kd * 32);
  }
  size_t koff[2], voff[2];
#pragma unroll
  for (int j = 0; j < 2; ++j) {
    int ci = tid + 512 * j;  // 0..1023
    koff[j] = ((size_t)bh * SEQ + (ci >> 5)) * HD + (((ci & 31) ^ ((ci >> 5) & 7)) * 8);
    voff[j] = ((size_t)bh * HD + (ci >> 2)) * SEQ + (((ci & 3) ^ ((ci >> 3) & 3)) * 8);
  }
  const int ldsb = w * 1024;

#define ASTAGE(buf, s0)                                                        \
  do {                                                                         \
    _Pragma("unroll") for (int j = 0; j < 2; ++j) {                            \
      async16((char*)&k_lds[buf][0] + ldsb + j * 8192,                         \
              kw + koff[j] + (size_t)(s0)*HD);                                 \
      async16((char*)&vT_lds[buf][0] + ldsb + j * 8192,                        \
              vTw + voff[j] + (size_t)(s0));                                   \
    }                                                                          \
  } while (0)

  f32x4 o[16] = {};
  const int nt = qx * 4 + 4;
  ASTAGE(0, 0);
  asm volatile("s_waitcnt vmcnt(0)" ::: "memory");
  __syncthreads();
  int cur = 0;
  for (int t = 0; t < nt; ++t) {
    const int s0 = t * 32;
    if (t + 1 < nt) ASTAGE(cur ^ 1, s0 + 32);
    // S = q . k^T  (16 rows x 32 cols per wave)
    f32x4 sf[2] = {};
#pragma unroll
    for (int fc = 0; fc < 2; ++fc) {
      const int R = fc * 16 + lr;
#pragma unroll
      for (int kd = 0; kd < 8; ++kd) {
        bf16x8 kb = *(const bf16x8*)&k_lds[cur][R * 256 + (((kd * 4 + (l >> 4)) ^ lr7) * 8)];
        sf[fc] = __builtin_amdgcn_mfma_f32_16x16x32_bf16(qf[kd], kb, sf[fc], 0, 0, 0);
      }
    }
    // decay mask + 1/scale, write P bf16 (wave-private rows, swizzled chunks)
#pragma unroll
    for (int fc = 0; fc < 2; ++fc) {
      int s_l = fc * 16 + lr;
      int chunk = s_l >> 3;
#pragma unroll
      for (int r = 0; r < 4; ++r) {
        int n_l = w * 16 + (l >> 4) * 4 + r;
        int dist = (q0 + n_l) - (s0 + s_l);
        float p = 0.0f;
        if (dist >= 0) p = sf[fc][r] * 0.0625f * exp2f((float)dist * log2g);
        P_lds[n_l * 32 + ((chunk ^ ((n_l >> 1) & 3)) * 8) + (s_l & 7)] = f2bf(p);
      }
    }
    // O += P . V   (same-wave RAW on P_lds ordered by lgkmcnt)
    bf16x8 pa = *(const bf16x8*)&P_lds[(w * 16 + lr) * 32 + cs_v8];
#pragma unroll
    for (int fd = 0; fd < 16; ++fd) {
      bf16x8 vb = *(const bf16x8*)&vT_lds[cur][(fd * 16 + lr) * 32 + cs_v8];
      o[fd] = __builtin_amdgcn_mfma_f32_16x16x32_bf16(pa, vb, o[fd], 0, 0, 0);
    }
    asm volatile("s_waitcnt vmcnt(0)" ::: "memory");
    __syncthreads();
    cur ^= 1;
  }
#undef ASTAGE
  size_t trow = (size_t)b * SEQ + q0 + w * 16 + (l >> 4) * 4;
#pragma unroll
  for (int fd = 0; fd < 16; ++fd) {
    int c = h * HD + fd * 16 + lr;
#pragma unroll
    for (int r = 0; r < 4; ++r)
      rtb[(trow + r) * HIDDEN + c] = f2bf(o[fd][r]);
  }
}

// ---------------- groupnorm + silu gate (in-place on bf16 ret) ----------------
__global__ __launch_bounds__(256) void k_gate(u16* __restrict__ rg,
                                              const u16* __restrict__ gw,
                                              const float* __restrict__ gnw,
                                              const float* __restrict__ gnb) {
  int g = blockIdx.x * 4 + (threadIdx.x >> 6);
  int l = threadIdx.x & 63;
  int t = g >> 3, h = g & 7;
  size_t base = (size_t)t * HIDDEN + h * HD + l * 4;
  ushort4 r4 = *(const ushort4*)(rg + base);
  float rv[4] = {bf2f(r4.x), bf2f(r4.y), bf2f(r4.z), bf2f(r4.w)};
  float s = rv[0] + rv[1] + rv[2] + rv[3];
  float sq = rv[0] * rv[0] + rv[1] * rv[1] + rv[2] * rv[2] + rv[3] * rv[3];
#pragma unroll
  for (int off = 32; off > 0; off >>= 1) {
    s += __shfl_xor(s, off);
    sq += __shfl_xor(sq, off);
  }
  float mean = s * (1.0f / 256.0f);
  float var = sq * (1.0f / 256.0f) - mean * mean;
  float rstd = rsqrtf(var + 1e-5f);
  int cb = h * HD + l * 4;
  float4 wv = *(const float4*)(gnw + cb);
  float4 bv = *(const float4*)(gnb + cb);
  ushort4 gg = *(const ushort4*)(gw + base);
  float gf[4] = {bf2f(gg.x), bf2f(gg.y), bf2f(gg.z), bf2f(gg.w)};
  float wa[4] = {wv.x, wv.y, wv.z, wv.w};
  float ba[4] = {bv.x, bv.y, bv.z, bv.w};
  ushort4 ov;
  u16* po = (u16*)&ov;
#pragma unroll
  for (int e = 0; e < 4; ++e) {
    float nrm = (rv[e] - mean) * rstd * wa[e] + ba[e];
    float gv = gf[e];
    float si = gv / (1.0f + expf(-gv));
    po[e] = f2bf(si * nrm);
  }
  *(ushort4*)(rg + base) = ov;
}

extern "C" void kernel_launch(void* const* d_in, const int* in_sizes, int n_in,
                              void* d_out, int out_size, void* d_ws, size_t ws_size,
                              hipStream_t stream) {
  (void)in_sizes; (void)n_in; (void)out_size; (void)ws_size;
  const float* x   = (const float*)d_in[0];
  const float* w_q = (const float*)d_in[1];
  const float* b_q = (const float*)d_in[2];
  const float* w_k = (const float*)d_in[3];
  const float* b_k = (const float*)d_in[4];
  const float* w_v = (const float*)d_in[5];
  const float* b_v = (const float*)d_in[6];
  const float* w_g = (const float*)d_in[7];
  const float* b_g = (const float*)d_in[8];
  const float* w_o = (const float*)d_in[9];
  const float* b_o = (const float*)d_in[10];
  const float* gnw = (const float*)d_in[11];
  const float* gnb = (const float*)d_in[12];

  // workspace layout — peak 200 MiB
  char* ws = (char*)d_ws;
  u16* xb   = (u16*)(ws);
  u16* wT   = (u16*)(ws + 33554432ULL);
  u16* qw   = (u16*)(ws + 75497472ULL);
  u16* kw   = (u16*)(ws + 109051904ULL);
  u16* vTw  = (u16*)(ws + 142606336ULL);
  u16* gw   = (u16*)(ws + 176160768ULL);
  u16* rtg  = xb;  // ret/gate reuse slot0 (xb dead after qkvg GEMM)

  const size_t WSZ = 4194304;  // elements per transposed weight matrix

  k_cvt_x<<<16384, 256, 0, stream>>>(x, xb);
  k_transpose<<<dim3(32, 32, 5), 256, 0, stream>>>(w_q, w_k, w_v, w_g, w_o, wT);
  k_gemm_qkvg<<<4096, 256, 0, stream>>>(xb, wT, b_q, b_k, b_v, b_g, qw, kw, vTw, gw);
  k_attn<<<512, 512, 0, stream>>>(qw, kw, vTw, rtg);
  k_gate<<<16384, 256, 0, stream>>>(rtg, gw, gnw, gnb);
  k_gemm_o<<<1024, 256, 0, stream>>>(rtg, wT + 4 * WSZ, b_o, (float*)d_out);
}